// Round 6
// baseline (53.384 us; speedup 1.0000x reference)
//
#include <hip/hip_runtime.h>

typedef float f32x4 __attribute__((ext_vector_type(4)));

__device__ __forceinline__ void nt_store(f32x4 v, f32x4* p) {
    __builtin_nontemporal_store(v, p);
}

__device__ __forceinline__ float tern(float w, float t) {
    return (fabsf(w) >= t) ? copysignf(1.f, w) : 0.f;
}

// Kernel A: one block, compute t = 0.7 * sum(|w|) / n into ws[0].
__global__ __launch_bounds__(1024) void threshold_kernel(
    const float* __restrict__ w, float* __restrict__ t_out, int n) {
    const int tid = threadIdx.x;
    const f32x4* w4 = reinterpret_cast<const f32x4*>(w);
    const int n4 = n >> 2;
    float s = 0.f;
    for (int i = tid; i < n4; i += 1024) {
        const f32x4 v = w4[i];
        s += fabsf(v.x) + fabsf(v.y) + fabsf(v.z) + fabsf(v.w);
    }
    #pragma unroll
    for (int off = 32; off > 0; off >>= 1) s += __shfl_xor(s, off, 64);
    __shared__ float partial[16];
    if ((tid & 63) == 0) partial[tid >> 6] = s;
    __syncthreads();
    if (tid == 0) {
        float tot = 0.f;
        #pragma unroll
        for (int k = 0; k < 16; ++k) tot += partial[k];
        t_out[0] = 0.7f * tot / (float)n;
    }
}

// Kernel B fast path: batch-unrolled x4 -> 4 independent loads in flight
// per wave before the dependent stores. Requires total4 % (4*stride) == 0.
__global__ __launch_bounds__(256) void scale_bias_stream4(
    const f32x4* __restrict__ x, const float* __restrict__ w,
    const f32x4* __restrict__ bias4, f32x4* __restrict__ out,
    const float* __restrict__ t_ptr, int n, long total4) {
    const int tid = threadIdx.x;
    const float t = t_ptr[0];

    const int n4 = n >> 2;
    const long i0 = (long)blockIdx.x * blockDim.x + tid;
    const long stride = (long)gridDim.x * blockDim.x;
    const int c = (int)(i0 & (long)(n4 - 1));

    const f32x4 wv = reinterpret_cast<const f32x4*>(w)[c];
    f32x4 qv;
    qv.x = tern(wv.x, t);
    qv.y = tern(wv.y, t);
    qv.z = tern(wv.z, t);
    qv.w = tern(wv.w, t);
    const f32x4 bv = bias4[c];

    for (long i = i0; i < total4; i += 4 * stride) {
        const f32x4 a = x[i];
        const f32x4 b = x[i + stride];
        const f32x4 c2 = x[i + 2 * stride];
        const f32x4 d = x[i + 3 * stride];
        nt_store(a * qv + bv, &out[i]);
        nt_store(b * qv + bv, &out[i + stride]);
        nt_store(c2 * qv + bv, &out[i + 2 * stride]);
        nt_store(d * qv + bv, &out[i + 3 * stride]);
    }
}

// Generic fallback: R5 kernel (one load at a time, bounds-safe).
__global__ __launch_bounds__(256) void scale_bias_stream(
    const f32x4* __restrict__ x, const float* __restrict__ w,
    const f32x4* __restrict__ bias4, f32x4* __restrict__ out,
    const float* __restrict__ t_ptr, int n, long total4) {
    const int tid = threadIdx.x;
    const float t = t_ptr[0];
    const int n4 = n >> 2;
    const long i0 = (long)blockIdx.x * blockDim.x + tid;
    const long stride = (long)gridDim.x * blockDim.x;
    const int c = (int)(i0 & (long)(n4 - 1));
    const f32x4 wv = reinterpret_cast<const f32x4*>(w)[c];
    f32x4 qv;
    qv.x = tern(wv.x, t);
    qv.y = tern(wv.y, t);
    qv.z = tern(wv.z, t);
    qv.w = tern(wv.w, t);
    const f32x4 bv = bias4[c];
    for (long i = i0; i < total4; i += stride) {
        nt_store(x[i] * qv + bv, &out[i]);
    }
}

extern "C" void kernel_launch(void* const* d_in, const int* in_sizes, int n_in,
                              void* d_out, int out_size, void* d_ws, size_t ws_size,
                              hipStream_t stream) {
    const float* x      = (const float*)d_in[0];
    const float* kernel = (const float*)d_in[1];
    const float* bias   = (const float*)d_in[2];
    float* out = (float*)d_out;
    float* t_ws = (float*)d_ws;

    const int N = in_sizes[1];          // 8192
    const long total4 = (long)out_size / 4;
    const long stride = 2048L * 256;

    threshold_kernel<<<1, 1024, 0, stream>>>(kernel, t_ws, N);

    if ((N & (N - 1)) == 0 && total4 % (4 * stride) == 0) {
        scale_bias_stream4<<<2048, 256, 0, stream>>>(
            (const f32x4*)x, kernel, (const f32x4*)bias, (f32x4*)out,
            t_ws, N, total4);
    } else {
        scale_bias_stream<<<2048, 256, 0, stream>>>(
            (const f32x4*)x, kernel, (const f32x4*)bias, (f32x4*)out,
            t_ws, N, total4);
    }
}

// Round 7
// 47.400 us; speedup vs baseline: 1.1262x; 1.1262x over previous
//
#include <hip/hip_runtime.h>

typedef float f32x4 __attribute__((ext_vector_type(4)));

__device__ __forceinline__ void nt_store(f32x4 v, f32x4* p) {
    __builtin_nontemporal_store(v, p);
}

__device__ __forceinline__ float tern(float w, float t) {
    return (fabsf(w) >= t) ? copysignf(1.f, w) : 0.f;
}

// Fused fast path (N == 8192): cheap redundant per-block threshold
// (8 f32x4 loads/thread, wave shuffle reduce, ONE barrier), then the
// R5 simple streaming loop (one load in flight — proven best in R6).
__global__ __launch_bounds__(256) void fused_cheap(
    const f32x4* __restrict__ x, const float* __restrict__ w,
    const f32x4* __restrict__ bias4, f32x4* __restrict__ out,
    int n, long total4) {
    const int tid = threadIdx.x;
    const f32x4* w4 = reinterpret_cast<const f32x4*>(w);

    // ---- threshold: 2048 f32x4 = 8 per thread ----
    float s = 0.f;
    #pragma unroll
    for (int k = 0; k < 8; ++k) {
        const f32x4 v = w4[tid + k * 256];
        s += fabsf(v.x) + fabsf(v.y) + fabsf(v.z) + fabsf(v.w);
    }
    #pragma unroll
    for (int off = 32; off > 0; off >>= 1) s += __shfl_xor(s, off, 64);
    __shared__ float partial[4];
    if ((tid & 63) == 0) partial[tid >> 6] = s;
    __syncthreads();
    const float t = 0.7f * (partial[0] + partial[1] + partial[2] + partial[3])
                    / (float)n;

    // ---- per-thread fixed column ----
    const int n4 = n >> 2;
    const long i0 = (long)blockIdx.x * blockDim.x + tid;
    const long stride = (long)gridDim.x * blockDim.x;
    const int c = (int)(i0 & (long)(n4 - 1));

    const f32x4 wv = w4[c];
    f32x4 qv;
    qv.x = tern(wv.x, t);
    qv.y = tern(wv.y, t);
    qv.z = tern(wv.z, t);
    qv.w = tern(wv.w, t);
    const f32x4 bv = bias4[c];

    // ---- R5 streaming loop, unchanged ----
    for (long i = i0; i < total4; i += stride) {
        nt_store(x[i] * qv + bv, &out[i]);
    }
}

// ---------- generic fallback: R5 split kernels ----------
__global__ __launch_bounds__(1024) void threshold_kernel(
    const float* __restrict__ w, float* __restrict__ t_out, int n) {
    const int tid = threadIdx.x;
    float s = 0.f;
    for (int i = tid; i < n; i += 1024) s += fabsf(w[i]);
    #pragma unroll
    for (int off = 32; off > 0; off >>= 1) s += __shfl_xor(s, off, 64);
    __shared__ float partial[16];
    if ((tid & 63) == 0) partial[tid >> 6] = s;
    __syncthreads();
    if (tid == 0) {
        float tot = 0.f;
        #pragma unroll
        for (int k = 0; k < 16; ++k) tot += partial[k];
        t_out[0] = 0.7f * tot / (float)n;
    }
}

__global__ __launch_bounds__(256) void scale_bias_stream(
    const f32x4* __restrict__ x, const float* __restrict__ w,
    const f32x4* __restrict__ bias4, f32x4* __restrict__ out,
    const float* __restrict__ t_ptr, int n, long total4) {
    const int tid = threadIdx.x;
    const float t = t_ptr[0];
    const int n4 = n >> 2;
    const long i0 = (long)blockIdx.x * blockDim.x + tid;
    const long stride = (long)gridDim.x * blockDim.x;
    for (long i = i0; i < total4; i += stride) {
        const int c = (int)(i % n4);
        const f32x4 wv = reinterpret_cast<const f32x4*>(w)[c];
        f32x4 qv;
        qv.x = tern(wv.x, t);
        qv.y = tern(wv.y, t);
        qv.z = tern(wv.z, t);
        qv.w = tern(wv.w, t);
        nt_store(x[i] * qv + bias4[c], &out[i]);
    }
}

extern "C" void kernel_launch(void* const* d_in, const int* in_sizes, int n_in,
                              void* d_out, int out_size, void* d_ws, size_t ws_size,
                              hipStream_t stream) {
    const float* x      = (const float*)d_in[0];
    const float* kernel = (const float*)d_in[1];
    const float* bias   = (const float*)d_in[2];
    float* out = (float*)d_out;
    float* t_ws = (float*)d_ws;

    const int N = in_sizes[1];          // 8192
    const long total4 = (long)out_size / 4;
    const long stride = 2048L * 256;

    if (N == 8192 && stride % (N / 4) == 0) {
        fused_cheap<<<2048, 256, 0, stream>>>(
            (const f32x4*)x, kernel, (const f32x4*)bias, (f32x4*)out,
            N, total4);
    } else {
        threshold_kernel<<<1, 1024, 0, stream>>>(kernel, t_ws, N);
        scale_bias_stream<<<2048, 256, 0, stream>>>(
            (const f32x4*)x, kernel, (const f32x4*)bias, (f32x4*)out,
            t_ws, N, total4);
    }
}

// Round 8
// 45.566 us; speedup vs baseline: 1.1716x; 1.0403x over previous
//
#include <hip/hip_runtime.h>

typedef float f32x4 __attribute__((ext_vector_type(4)));

__device__ __forceinline__ void nt_store(f32x4 v, f32x4* p) {
    __builtin_nontemporal_store(v, p);
}

__device__ __forceinline__ float tern(float w, float t) {
    return (fabsf(w) >= t) ? copysignf(1.f, w) : 0.f;
}

// Fused fast path (N == 8192): 1024-thread blocks -> 4x fewer prologue
// replicas than R7 (512 vs 2048 redundant w-reductions). Stream loop
// identical to R7's (one load in flight — proven best in R6).
__global__ __launch_bounds__(1024) void fused_cheap_1k(
    const f32x4* __restrict__ x, const float* __restrict__ w,
    const f32x4* __restrict__ bias4, f32x4* __restrict__ out,
    int n, long total4) {
    const int tid = threadIdx.x;
    const f32x4* w4 = reinterpret_cast<const f32x4*>(w);

    // ---- threshold: 2048 f32x4 = 2 per thread ----
    float s = 0.f;
    #pragma unroll
    for (int k = 0; k < 2; ++k) {
        const f32x4 v = w4[tid + k * 1024];
        s += fabsf(v.x) + fabsf(v.y) + fabsf(v.z) + fabsf(v.w);
    }
    #pragma unroll
    for (int off = 32; off > 0; off >>= 1) s += __shfl_xor(s, off, 64);
    __shared__ float partial[16];
    if ((tid & 63) == 0) partial[tid >> 6] = s;
    __syncthreads();
    float tot = 0.f;
    #pragma unroll
    for (int k = 0; k < 16; ++k) tot += partial[k];
    const float t = 0.7f * tot / (float)n;

    // ---- per-thread fixed column ----
    const int n4 = n >> 2;
    const long i0 = (long)blockIdx.x * blockDim.x + tid;
    const long stride = (long)gridDim.x * blockDim.x;
    const int c = (int)(i0 & (long)(n4 - 1));

    const f32x4 wv = w4[c];
    f32x4 qv;
    qv.x = tern(wv.x, t);
    qv.y = tern(wv.y, t);
    qv.z = tern(wv.z, t);
    qv.w = tern(wv.w, t);
    const f32x4 bv = bias4[c];

    // ---- streaming loop, unchanged from R7 ----
    for (long i = i0; i < total4; i += stride) {
        nt_store(x[i] * qv + bv, &out[i]);
    }
}

// ---------- generic fallback: R5 split kernels ----------
__global__ __launch_bounds__(1024) void threshold_kernel(
    const float* __restrict__ w, float* __restrict__ t_out, int n) {
    const int tid = threadIdx.x;
    float s = 0.f;
    for (int i = tid; i < n; i += 1024) s += fabsf(w[i]);
    #pragma unroll
    for (int off = 32; off > 0; off >>= 1) s += __shfl_xor(s, off, 64);
    __shared__ float partial[16];
    if ((tid & 63) == 0) partial[tid >> 6] = s;
    __syncthreads();
    if (tid == 0) {
        float tot = 0.f;
        #pragma unroll
        for (int k = 0; k < 16; ++k) tot += partial[k];
        t_out[0] = 0.7f * tot / (float)n;
    }
}

__global__ __launch_bounds__(256) void scale_bias_stream(
    const f32x4* __restrict__ x, const float* __restrict__ w,
    const f32x4* __restrict__ bias4, f32x4* __restrict__ out,
    const float* __restrict__ t_ptr, int n, long total4) {
    const int tid = threadIdx.x;
    const float t = t_ptr[0];
    const int n4 = n >> 2;
    const long i0 = (long)blockIdx.x * blockDim.x + tid;
    const long stride = (long)gridDim.x * blockDim.x;
    for (long i = i0; i < total4; i += stride) {
        const int c = (int)(i % n4);
        const f32x4 wv = reinterpret_cast<const f32x4*>(w)[c];
        f32x4 qv;
        qv.x = tern(wv.x, t);
        qv.y = tern(wv.y, t);
        qv.z = tern(wv.z, t);
        qv.w = tern(wv.w, t);
        nt_store(x[i] * qv + bias4[c], &out[i]);
    }
}

extern "C" void kernel_launch(void* const* d_in, const int* in_sizes, int n_in,
                              void* d_out, int out_size, void* d_ws, size_t ws_size,
                              hipStream_t stream) {
    const float* x      = (const float*)d_in[0];
    const float* kernel = (const float*)d_in[1];
    const float* bias   = (const float*)d_in[2];
    float* out = (float*)d_out;
    float* t_ws = (float*)d_ws;

    const int N = in_sizes[1];          // 8192
    const long total4 = (long)out_size / 4;
    const long stride = 512L * 1024;

    if (N == 8192 && stride % (N / 4) == 0) {
        fused_cheap_1k<<<512, 1024, 0, stream>>>(
            (const f32x4*)x, kernel, (const f32x4*)bias, (f32x4*)out,
            N, total4);
    } else {
        threshold_kernel<<<1, 1024, 0, stream>>>(kernel, t_ws, N);
        scale_bias_stream<<<2048, 256, 0, stream>>>(
            (const f32x4*)x, kernel, (const f32x4*)bias, (f32x4*)out,
            t_ws, N, total4);
    }
}

// Round 9
// 44.995 us; speedup vs baseline: 1.1864x; 1.0127x over previous
//
#include <hip/hip_runtime.h>

typedef float f32x4 __attribute__((ext_vector_type(4)));

__device__ __forceinline__ void nt_store(f32x4 v, f32x4* p) {
    __builtin_nontemporal_store(v, p);
}

__device__ __forceinline__ float tern(float w, float t) {
    return (fabsf(w) >= t) ? copysignf(1.f, w) : 0.f;
}

// R8 + single change: prefetch the first 2 x-iterations BEFORE the
// w-reduction so the stream starts at cycle 0; drain after qv/bv ready.
__global__ __launch_bounds__(1024) void fused_cheap_1k_pf(
    const f32x4* __restrict__ x, const float* __restrict__ w,
    const f32x4* __restrict__ bias4, f32x4* __restrict__ out,
    int n, long total4) {
    const int tid = threadIdx.x;
    const f32x4* w4 = reinterpret_cast<const f32x4*>(w);

    const int n4 = n >> 2;
    const long i0 = (long)blockIdx.x * blockDim.x + tid;
    const long stride = (long)gridDim.x * blockDim.x;
    const int c = (int)(i0 & (long)(n4 - 1));

    // ---- issue x prefetch first: HBM latency hides under the reduce ----
    const f32x4 x0 = x[i0];
    const f32x4 x1 = x[i0 + stride];

    // ---- threshold: 2048 f32x4 = 2 per thread, shuffle reduce, 1 barrier ----
    float s = 0.f;
    #pragma unroll
    for (int k = 0; k < 2; ++k) {
        const f32x4 v = w4[tid + k * 1024];
        s += fabsf(v.x) + fabsf(v.y) + fabsf(v.z) + fabsf(v.w);
    }
    #pragma unroll
    for (int off = 32; off > 0; off >>= 1) s += __shfl_xor(s, off, 64);
    __shared__ float partial[16];
    if ((tid & 63) == 0) partial[tid >> 6] = s;
    __syncthreads();
    float tot = 0.f;
    #pragma unroll
    for (int k = 0; k < 16; ++k) tot += partial[k];
    const float t = 0.7f * tot / (float)n;

    const f32x4 wv = w4[c];
    f32x4 qv;
    qv.x = tern(wv.x, t);
    qv.y = tern(wv.y, t);
    qv.z = tern(wv.z, t);
    qv.w = tern(wv.w, t);
    const f32x4 bv = bias4[c];

    // ---- drain prefetched iterations ----
    nt_store(x0 * qv + bv, &out[i0]);
    nt_store(x1 * qv + bv, &out[i0 + stride]);

    // ---- remaining iterations, same simple loop as R8 ----
    for (long i = i0 + 2 * stride; i < total4; i += stride) {
        nt_store(x[i] * qv + bv, &out[i]);
    }
}

// ---------- generic fallback: R5 split kernels ----------
__global__ __launch_bounds__(1024) void threshold_kernel(
    const float* __restrict__ w, float* __restrict__ t_out, int n) {
    const int tid = threadIdx.x;
    float s = 0.f;
    for (int i = tid; i < n; i += 1024) s += fabsf(w[i]);
    #pragma unroll
    for (int off = 32; off > 0; off >>= 1) s += __shfl_xor(s, off, 64);
    __shared__ float partial[16];
    if ((tid & 63) == 0) partial[tid >> 6] = s;
    __syncthreads();
    if (tid == 0) {
        float tot = 0.f;
        #pragma unroll
        for (int k = 0; k < 16; ++k) tot += partial[k];
        t_out[0] = 0.7f * tot / (float)n;
    }
}

__global__ __launch_bounds__(256) void scale_bias_stream(
    const f32x4* __restrict__ x, const float* __restrict__ w,
    const f32x4* __restrict__ bias4, f32x4* __restrict__ out,
    const float* __restrict__ t_ptr, int n, long total4) {
    const int tid = threadIdx.x;
    const float t = t_ptr[0];
    const int n4 = n >> 2;
    const long i0 = (long)blockIdx.x * blockDim.x + tid;
    const long stride = (long)gridDim.x * blockDim.x;
    for (long i = i0; i < total4; i += stride) {
        const int c = (int)(i % n4);
        const f32x4 wv = reinterpret_cast<const f32x4*>(w)[c];
        f32x4 qv;
        qv.x = tern(wv.x, t);
        qv.y = tern(wv.y, t);
        qv.z = tern(wv.z, t);
        qv.w = tern(wv.w, t);
        nt_store(x[i] * qv + bias4[c], &out[i]);
    }
}

extern "C" void kernel_launch(void* const* d_in, const int* in_sizes, int n_in,
                              void* d_out, int out_size, void* d_ws, size_t ws_size,
                              hipStream_t stream) {
    const float* x      = (const float*)d_in[0];
    const float* kernel = (const float*)d_in[1];
    const float* bias   = (const float*)d_in[2];
    float* out = (float*)d_out;
    float* t_ws = (float*)d_ws;

    const int N = in_sizes[1];          // 8192
    const long total4 = (long)out_size / 4;
    const long stride = 512L * 1024;

    if (N == 8192 && stride % (N / 4) == 0 && total4 >= 2 * stride) {
        fused_cheap_1k_pf<<<512, 1024, 0, stream>>>(
            (const f32x4*)x, kernel, (const f32x4*)bias, (f32x4*)out,
            N, total4);
    } else {
        threshold_kernel<<<1, 1024, 0, stream>>>(kernel, t_ws, N);
        scale_bias_stream<<<2048, 256, 0, stream>>>(
            (const f32x4*)x, kernel, (const f32x4*)bias, (f32x4*)out,
            t_ws, N, total4);
    }
}